// Round 1
// baseline (379.182 us; speedup 1.0000x reference)
//
#include <hip/hip_runtime.h>
#include <hip/hip_bf16.h>

// SirenLinear: out[b,r] = sum_c x[b,c] * W[r,c] + bias[r]
//   W[r,c] = b3 + h2 . W3,  h2 = sin(30*(W2 h1 + b2)),  h1 = sin(30*(W1 e + b1))
//   e = embedded_coords[r*1024+c]  (18 floats)
//
// Pipeline: cast_x (fp32->bf16) ; siren_w (fp32 VALU, writes W as bf16) ;
//           gemm (bf16 MFMA 16x16x32, 128x128 tile, global_load_lds w=16,
//                 XOR-swizzled LDS since padding breaks global_load_lds).

typedef __attribute__((ext_vector_type(8))) short bf16x8;
typedef __attribute__((ext_vector_type(4))) float f32x4;

__device__ __forceinline__ unsigned short f2bf(float f) {
    union { float f; unsigned u; } v; v.f = f;
    unsigned r = v.u + 0x7fffu + ((v.u >> 16) & 1u);   // RNE
    return (unsigned short)(r >> 16);
}

__device__ __forceinline__ void async_ld16(const void* g, void* l) {
    __builtin_amdgcn_global_load_lds(
        (__attribute__((address_space(1))) void*)g,
        (__attribute__((address_space(3))) void*)l, 16, 0, 0);
}

// ---------------- cast x fp32 -> bf16 ----------------
__global__ __launch_bounds__(256) void cast_x_kernel(
        const float4* __restrict__ x, unsigned short* __restrict__ xb) {
    long i = (long)blockIdx.x * 256 + threadIdx.x;   // one float4 per thread
    float4 v = x[i];
    ushort4 o;
    o.x = f2bf(v.x); o.y = f2bf(v.y); o.z = f2bf(v.z); o.w = f2bf(v.w);
    *(ushort4*)(xb + i * 4) = o;
}

// ---------------- stage A: generate W (bf16) ----------------
__global__ __launch_bounds__(256) void siren_w_kernel(
        const float* __restrict__ ec,
        const float* __restrict__ W1, const float* __restrict__ b1,
        const float* __restrict__ W2, const float* __restrict__ b2,
        const float* __restrict__ W3, const float* __restrict__ b3,
        unsigned short* __restrict__ Wout) {
    long p = (long)blockIdx.x * 256 + threadIdx.x;   // point index, 1M total

    // load 18-dim embedding (8B-aligned: 18 floats = 72B per row)
    float e[18];
    const float2* ep = (const float2*)(ec + p * 18);
    #pragma unroll
    for (int i = 0; i < 9; ++i) { float2 v = ep[i]; e[2*i] = v.x; e[2*i+1] = v.y; }

    // layer 1: h1[j] = sin(30*(W1[j,:] . e + b1[j]))   -- W1 reads wave-uniform
    float h[64];
    for (int j = 0; j < 64; ++j) {
        const float* wr = W1 + j * 18;
        float z0 = b1[j], z1 = 0.f;
        #pragma unroll
        for (int i = 0; i < 9; ++i) { z0 += e[2*i] * wr[2*i]; z1 += e[2*i+1] * wr[2*i+1]; }
        h[j] = __sinf(30.f * (z0 + z1));
    }

    // layer 2 + head, streaming: w += W3[i]*sin(30*(W2[i,:] . h + b2[i]))
    float w = b3[0];
    for (int i = 0; i < 64; ++i) {
        const float4* w2r = (const float4*)(W2 + i * 64);   // wave-uniform
        float z0 = b2[i], z1 = 0.f, z2 = 0.f, z3 = 0.f;     // 4 partials: break dep chain
        #pragma unroll
        for (int c = 0; c < 16; ++c) {
            float4 v = w2r[c];
            z0 += v.x * h[4*c + 0];
            z1 += v.y * h[4*c + 1];
            z2 += v.z * h[4*c + 2];
            z3 += v.w * h[4*c + 3];
        }
        w += W3[i] * __sinf(30.f * ((z0 + z1) + (z2 + z3)));
    }
    Wout[p] = f2bf(w);
}

// ---------------- stage B: out = x @ W^T + bias (bf16 MFMA) ----------------
// A = x_bf16 [8192][1024] K-contig; B = W_bf16 [1024][1024] (n=r, k=c) K-contig.
// Block: 256 thr = 4 waves (2x2 of 64x64), tile 128x128, BK=32.
// LDS chunk swizzle: row r (64B = 4 x 16B chunks), stored chunk p holds logical
// chunk p ^ ((r>>1)&3). Staging lane loads the matching global chunk so the
// forced-linear global_load_lds layout lands swizzled; ds_read_b128 bank starts
// then cover all 8 positions -> 2 words/bank (free, m136).
__global__ __launch_bounds__(256) void gemm_kernel(
        const unsigned short* __restrict__ A,
        const unsigned short* __restrict__ B,
        const float* __restrict__ bias,
        float* __restrict__ C) {
    const int K = 1024;
    __shared__ __align__(16) unsigned short As[128 * 32];
    __shared__ __align__(16) unsigned short Bs[128 * 32];

    int tid  = threadIdx.x;
    int lane = tid & 63;
    int wv   = tid >> 6;
    int wm   = wv & 1, wn = wv >> 1;
    long Abase = (long)blockIdx.x * 128 * K;
    long Bbase = (long)blockIdx.y * 128 * K;

    int sr = tid >> 2;      // staging row 0..63 (+64 on round q=1)
    int sc = tid & 3;       // staging chunk slot
    int rsel = lane & 15;   // fragment row/col within 16
    int csel = lane >> 4;   // fragment k-chunk 0..3

    f32x4 acc[4][4] = {};

    for (int kt = 0; kt < K; kt += 32) {
        #pragma unroll
        for (int q = 0; q < 2; ++q) {
            int row = q * 64 + sr;
            int cc  = sc ^ ((row >> 1) & 3);                 // global chunk to fetch
            const unsigned short* ga = A + Abase + (long)row * K + kt + cc * 8;
            const unsigned short* gb = B + Bbase + (long)row * K + kt + cc * 8;
            unsigned short* la = &As[(q * 256 + wv * 64) * 8];  // wave-uniform base
            unsigned short* lb = &Bs[(q * 256 + wv * 64) * 8];
            async_ld16(ga, la);
            async_ld16(gb, lb);
        }
        __syncthreads();   // compiler drains vmcnt before s_barrier

        bf16x8 af[4], bf[4];
        #pragma unroll
        for (int mi = 0; mi < 4; ++mi) {
            int row = wm * 64 + mi * 16 + rsel;
            int ch  = csel ^ ((row >> 1) & 3);
            af[mi] = *(const bf16x8*)&As[row * 32 + ch * 8];
        }
        #pragma unroll
        for (int ni = 0; ni < 4; ++ni) {
            int row = wn * 64 + ni * 16 + rsel;
            int ch  = csel ^ ((row >> 1) & 3);
            bf[ni] = *(const bf16x8*)&Bs[row * 32 + ch * 8];
        }
        #pragma unroll
        for (int mi = 0; mi < 4; ++mi)
            #pragma unroll
            for (int ni = 0; ni < 4; ++ni)
                acc[mi][ni] = __builtin_amdgcn_mfma_f32_16x16x32_bf16(
                    af[mi], bf[ni], acc[mi][ni], 0, 0, 0);
        __syncthreads();
    }

    // epilogue: C/D layout col=lane&15, row=(lane>>4)*4+reg  (m89/m91 verified)
    int row0 = blockIdx.x * 128 + wm * 64;
    int col0 = blockIdx.y * 128 + wn * 64;
    #pragma unroll
    for (int ni = 0; ni < 4; ++ni) {
        int col = col0 + ni * 16 + rsel;
        float bv = bias[col];
        #pragma unroll
        for (int mi = 0; mi < 4; ++mi) {
            int rbase = row0 + mi * 16 + csel * 4;
            #pragma unroll
            for (int r = 0; r < 4; ++r)
                C[(long)(rbase + r) * 1024 + col] = acc[mi][ni][r] + bv;
        }
    }
}

extern "C" void kernel_launch(void* const* d_in, const int* in_sizes, int n_in,
                              void* d_out, int out_size, void* d_ws, size_t ws_size,
                              hipStream_t stream) {
    const float* x    = (const float*)d_in[0];
    const float* ec   = (const float*)d_in[1];
    const float* W1   = (const float*)d_in[2];
    const float* b1   = (const float*)d_in[3];
    const float* W2   = (const float*)d_in[4];
    const float* b2   = (const float*)d_in[5];
    const float* W3   = (const float*)d_in[6];
    const float* b3   = (const float*)d_in[7];
    const float* bias = (const float*)d_in[8];
    float* out = (float*)d_out;

    unsigned short* xb = (unsigned short*)d_ws;            // 8192*1024 bf16 = 16 MB
    unsigned short* Wb = xb + (size_t)8192 * 1024;         // 1024*1024 bf16 = 2 MB

    cast_x_kernel<<<8192, 256, 0, stream>>>((const float4*)x, xb);
    siren_w_kernel<<<4096, 256, 0, stream>>>(ec, W1, b1, W2, b2, W3, b3, Wb);
    dim3 g(64, 8);
    gemm_kernel<<<g, 256, 0, stream>>>(xb, Wb, bias, out);
}

// Round 2
// 305.716 us; speedup vs baseline: 1.2403x; 1.2403x over previous
//
#include <hip/hip_runtime.h>
#include <hip/hip_bf16.h>

// SirenLinear: out[b,r] = sum_c x[b,c] * W[r,c] + bias[r]
//   W[r,c] = b3 + h2 . W3,  h2 = sin(30*(W2 h1 + b2)),  h1 = sin(30*(W1 e + b1))
//   e = embedded_coords[r*1024+c]  (18 floats, separable in (y(r), x(c)))
//
// Stage A exploits exact affine separability of layer 1:
//   z1(r,c) = z1(r,0) + [z1(0,c) - z1(0,0)]   (y-parts cancel exactly)
// so a 0.5 MB table pair replaces the 72 MB ec stream + 1152 FMA/point.
// Layer 1 is fully unrolled so h[64] stays in VGPRs (round-1 bug: dynamic
// indexing spilled h to scratch -> 48 VGPRs, 3.3x slowdown).

typedef __attribute__((ext_vector_type(8))) short bf16x8;
typedef __attribute__((ext_vector_type(4))) float f32x4;

__device__ __forceinline__ unsigned short f2bf(float f) {
    union { float f; unsigned u; } v; v.f = f;
    unsigned r = v.u + 0x7fffu + ((v.u >> 16) & 1u);   // RNE
    return (unsigned short)(r >> 16);
}

__device__ __forceinline__ void async_ld16(const void* g, void* l) {
    __builtin_amdgcn_global_load_lds(
        (__attribute__((address_space(1))) void*)g,
        (__attribute__((address_space(3))) void*)l, 16, 0, 0);
}

// ---------------- cast x fp32 -> bf16 ----------------
__global__ __launch_bounds__(256) void cast_x_kernel(
        const float4* __restrict__ x, unsigned short* __restrict__ xb) {
    long i = (long)blockIdx.x * 256 + threadIdx.x;   // one float4 per thread
    float4 v = x[i];
    ushort4 o;
    o.x = f2bf(v.x); o.y = f2bf(v.y); o.z = f2bf(v.z); o.w = f2bf(v.w);
    *(ushort4*)(xb + i * 4) = o;
}

// ---------------- stage A0: layer-1 separability tables ----------------
// Zrow[r][j] = W1[j,:] . e(r,0) + b1[j]
// Zcol[c][j] = W1[j,:] . (e(0,c) - e(0,0))      (y-components cancel exactly)
__global__ __launch_bounds__(256) void siren_tables_kernel(
        const float* __restrict__ ec,
        const float* __restrict__ W1, const float* __restrict__ b1,
        float* __restrict__ Zrow, float* __restrict__ Zcol) {
    int t = blockIdx.x * 256 + threadIdx.x;          // 0..2047
    float e[18];
    if (t < 1024) {
        const float* pe = ec + (long)t * 1024 * 18;  // point (r=t, c=0)
        #pragma unroll
        for (int i = 0; i < 18; ++i) e[i] = pe[i];
        for (int j = 0; j < 64; ++j) {
            float z = b1[j];
            #pragma unroll
            for (int i = 0; i < 18; ++i) z += W1[j * 18 + i] * e[i];
            Zrow[t * 64 + j] = z;
        }
    } else {
        int c = t - 1024;
        const float* pe = ec + (long)c * 18;         // point (r=0, c)
        #pragma unroll
        for (int i = 0; i < 18; ++i) e[i] = pe[i] - ec[i];
        for (int j = 0; j < 64; ++j) {
            float z = 0.f;
            #pragma unroll
            for (int i = 0; i < 18; ++i) z += W1[j * 18 + i] * e[i];
            Zcol[c * 64 + j] = z;
        }
    }
}

// ---------------- stage A: generate W (bf16) ----------------
__global__ __launch_bounds__(256) void siren_w_kernel(
        const float* __restrict__ Zrow, const float* __restrict__ Zcol,
        const float* __restrict__ W2, const float* __restrict__ b2,
        const float* __restrict__ W3, const float* __restrict__ b3,
        unsigned short* __restrict__ Wout) {
    long p = (long)blockIdx.x * 256 + threadIdx.x;   // point index, 1M total
    int r = blockIdx.x >> 2;                         // block-uniform row (256 | 1024)
    int c = (int)(p & 1023);

    const float4* zr = (const float4*)(Zrow + r * 64);   // uniform -> scalar loads
    const float4* zc = (const float4*)(Zcol + (long)c * 64);

    // layer 1: h[j] = sin(30*(Zrow[r][j] + Zcol[c][j])) -- fully unrolled, h in VGPRs
    float h[64];
    #pragma unroll
    for (int q = 0; q < 16; ++q) {
        float4 a = zr[q];
        float4 b = zc[q];
        h[4*q + 0] = __sinf(30.f * (a.x + b.x));
        h[4*q + 1] = __sinf(30.f * (a.y + b.y));
        h[4*q + 2] = __sinf(30.f * (a.z + b.z));
        h[4*q + 3] = __sinf(30.f * (a.w + b.w));
    }

    // layer 2 + head, streaming: w += W3[i]*sin(30*(W2[i,:] . h + b2[i]))
    float w = b3[0];
    for (int i = 0; i < 64; ++i) {
        const float4* w2r = (const float4*)(W2 + i * 64);   // wave-uniform
        float z0 = b2[i], z1 = 0.f, z2 = 0.f, z3 = 0.f;     // 4 partials
        #pragma unroll
        for (int q = 0; q < 16; ++q) {
            float4 v = w2r[q];
            z0 += v.x * h[4*q + 0];
            z1 += v.y * h[4*q + 1];
            z2 += v.z * h[4*q + 2];
            z3 += v.w * h[4*q + 3];
        }
        w += W3[i] * __sinf(30.f * ((z0 + z1) + (z2 + z3)));
    }
    Wout[p] = f2bf(w);
}

// ---------------- stage B: out = x @ W^T + bias (bf16 MFMA) ----------------
// A = x_bf16 [8192][1024] K-contig; B = W_bf16 [1024][1024] (n=r, k=c) K-contig.
// Block: 256 thr = 4 waves (2x2 of 64x64), tile 128x128, BK=32.
// LDS chunk swizzle: row r (64B = 4 x 16B chunks), stored chunk p holds logical
// chunk p ^ ((r>>1)&3); staging lane fetches the matching global chunk.
__global__ __launch_bounds__(256) void gemm_kernel(
        const unsigned short* __restrict__ A,
        const unsigned short* __restrict__ B,
        const float* __restrict__ bias,
        float* __restrict__ C) {
    const int K = 1024;
    __shared__ __align__(16) unsigned short As[128 * 32];
    __shared__ __align__(16) unsigned short Bs[128 * 32];

    int tid  = threadIdx.x;
    int lane = tid & 63;
    int wv   = tid >> 6;
    int wm   = wv & 1, wn = wv >> 1;
    long Abase = (long)blockIdx.x * 128 * K;
    long Bbase = (long)blockIdx.y * 128 * K;

    int sr = tid >> 2;      // staging row 0..63 (+64 on round q=1)
    int sc = tid & 3;       // staging chunk slot
    int rsel = lane & 15;   // fragment row/col within 16
    int csel = lane >> 4;   // fragment k-chunk 0..3

    f32x4 acc[4][4] = {};

    for (int kt = 0; kt < K; kt += 32) {
        #pragma unroll
        for (int q = 0; q < 2; ++q) {
            int row = q * 64 + sr;
            int cc  = sc ^ ((row >> 1) & 3);                 // global chunk to fetch
            const unsigned short* ga = A + Abase + (long)row * K + kt + cc * 8;
            const unsigned short* gb = B + Bbase + (long)row * K + kt + cc * 8;
            unsigned short* la = &As[(q * 256 + wv * 64) * 8];  // wave-uniform base
            unsigned short* lb = &Bs[(q * 256 + wv * 64) * 8];
            async_ld16(ga, la);
            async_ld16(gb, lb);
        }
        __syncthreads();

        bf16x8 af[4], bf[4];
        #pragma unroll
        for (int mi = 0; mi < 4; ++mi) {
            int row = wm * 64 + mi * 16 + rsel;
            int ch  = csel ^ ((row >> 1) & 3);
            af[mi] = *(const bf16x8*)&As[row * 32 + ch * 8];
        }
        #pragma unroll
        for (int ni = 0; ni < 4; ++ni) {
            int row = wn * 64 + ni * 16 + rsel;
            int ch  = csel ^ ((row >> 1) & 3);
            bf[ni] = *(const bf16x8*)&Bs[row * 32 + ch * 8];
        }
        #pragma unroll
        for (int mi = 0; mi < 4; ++mi)
            #pragma unroll
            for (int ni = 0; ni < 4; ++ni)
                acc[mi][ni] = __builtin_amdgcn_mfma_f32_16x16x32_bf16(
                    af[mi], bf[ni], acc[mi][ni], 0, 0, 0);
        __syncthreads();
    }

    // epilogue: C/D layout col=lane&15, row=(lane>>4)*4+reg  (m89/m91 verified)
    int row0 = blockIdx.x * 128 + wm * 64;
    int col0 = blockIdx.y * 128 + wn * 64;
    #pragma unroll
    for (int ni = 0; ni < 4; ++ni) {
        int col = col0 + ni * 16 + rsel;
        float bv = bias[col];
        #pragma unroll
        for (int mi = 0; mi < 4; ++mi) {
            int rbase = row0 + mi * 16 + csel * 4;
            #pragma unroll
            for (int r = 0; r < 4; ++r)
                C[(long)(rbase + r) * 1024 + col] = acc[mi][ni][r] + bv;
        }
    }
}

extern "C" void kernel_launch(void* const* d_in, const int* in_sizes, int n_in,
                              void* d_out, int out_size, void* d_ws, size_t ws_size,
                              hipStream_t stream) {
    const float* x    = (const float*)d_in[0];
    const float* ec   = (const float*)d_in[1];
    const float* W1   = (const float*)d_in[2];
    const float* b1   = (const float*)d_in[3];
    const float* W2   = (const float*)d_in[4];
    const float* b2   = (const float*)d_in[5];
    const float* W3   = (const float*)d_in[6];
    const float* b3   = (const float*)d_in[7];
    const float* bias = (const float*)d_in[8];
    float* out = (float*)d_out;

    unsigned short* xb = (unsigned short*)d_ws;            // 8192*1024 bf16 = 16 MB
    unsigned short* Wb = xb + (size_t)8192 * 1024;         // 1024*1024 bf16 = 2 MB
    float* Zrow = (float*)(Wb + (size_t)1024 * 1024);      // 1024*64 f32 = 256 KB
    float* Zcol = Zrow + 1024 * 64;                        // 1024*64 f32 = 256 KB

    cast_x_kernel<<<8192, 256, 0, stream>>>((const float4*)x, xb);
    siren_tables_kernel<<<8, 256, 0, stream>>>(ec, W1, b1, Zrow, Zcol);
    siren_w_kernel<<<4096, 256, 0, stream>>>(Zrow, Zcol, W2, b2, W3, b3, Wb);
    dim3 g(64, 8);
    gemm_kernel<<<g, 256, 0, stream>>>(xb, Wb, bias, out);
}

// Round 3
// 282.052 us; speedup vs baseline: 1.3444x; 1.0839x over previous
//
#include <hip/hip_runtime.h>
#include <hip/hip_bf16.h>

// SirenLinear: out[b,r] = sum_c x[b,c] * W[r,c] + bias[r]
//   W[r,c] = b3 + h2 . W3,  h2 = sin(30*(W2 h1 + b2)),  h1 = sin(30*(W1 e + b1))
//
// Stage A exploits exact affine separability of layer 1:
//   z1(r,c) = z1(r,0) + [z1(0,c) - z1(0,0)]
// Round-2 lesson: __launch_bounds__(256) alone budgets only 48 VGPRs ->
// h[64] spilled to AGPRs (VALUBusy wasted on accvgpr moves). Fix: explicit
// min-waves arg (256,3) -> ~170 VGPR budget, h stays in VGPRs. Layer-2 math
// on float2 vector types so the backend can emit v_pk_fma_f32 (2 FMA/instr).

typedef __attribute__((ext_vector_type(8))) short bf16x8;
typedef __attribute__((ext_vector_type(4))) float f32x4;
typedef __attribute__((ext_vector_type(2))) float f32x2;

__device__ __forceinline__ unsigned short f2bf(float f) {
    union { float f; unsigned u; } v; v.f = f;
    unsigned r = v.u + 0x7fffu + ((v.u >> 16) & 1u);   // RNE
    return (unsigned short)(r >> 16);
}

__device__ __forceinline__ void async_ld16(const void* g, void* l) {
    __builtin_amdgcn_global_load_lds(
        (__attribute__((address_space(1))) void*)g,
        (__attribute__((address_space(3))) void*)l, 16, 0, 0);
}

// ---------------- cast x fp32 -> bf16 ----------------
__global__ __launch_bounds__(256) void cast_x_kernel(
        const float4* __restrict__ x, unsigned short* __restrict__ xb) {
    long i = (long)blockIdx.x * 256 + threadIdx.x;   // one float4 per thread
    float4 v = x[i];
    ushort4 o;
    o.x = f2bf(v.x); o.y = f2bf(v.y); o.z = f2bf(v.z); o.w = f2bf(v.w);
    *(ushort4*)(xb + i * 4) = o;
}

// ---------------- stage A0: layer-1 separability tables ----------------
// Zrow[r][j] = W1[j,:] . e(r,0) + b1[j]
// Zcol[c][j] = W1[j,:] . (e(0,c) - e(0,0))      (y-components cancel exactly)
__global__ __launch_bounds__(256) void siren_tables_kernel(
        const float* __restrict__ ec,
        const float* __restrict__ W1, const float* __restrict__ b1,
        float* __restrict__ Zrow, float* __restrict__ Zcol) {
    int t = blockIdx.x * 256 + threadIdx.x;          // 0..2047
    float e[18];
    if (t < 1024) {
        const float* pe = ec + (long)t * 1024 * 18;  // point (r=t, c=0)
        #pragma unroll
        for (int i = 0; i < 18; ++i) e[i] = pe[i];
        for (int j = 0; j < 64; ++j) {
            float z = b1[j];
            #pragma unroll
            for (int i = 0; i < 18; ++i) z += W1[j * 18 + i] * e[i];
            Zrow[t * 64 + j] = z;
        }
    } else {
        int c = t - 1024;
        const float* pe = ec + (long)c * 18;         // point (r=0, c)
        #pragma unroll
        for (int i = 0; i < 18; ++i) e[i] = pe[i] - ec[i];
        for (int j = 0; j < 64; ++j) {
            float z = 0.f;
            #pragma unroll
            for (int i = 0; i < 18; ++i) z += W1[j * 18 + i] * e[i];
            Zcol[c * 64 + j] = z;
        }
    }
}

// ---------------- stage A: generate W (bf16) ----------------
__global__ __launch_bounds__(256, 3) void siren_w_kernel(
        const float* __restrict__ Zrow, const float* __restrict__ Zcol,
        const float* __restrict__ W2, const float* __restrict__ b2,
        const float* __restrict__ W3, const float* __restrict__ b3,
        unsigned short* __restrict__ Wout) {
    long p = (long)blockIdx.x * 256 + threadIdx.x;   // point index, 1M total
    int r = blockIdx.x >> 2;                         // block-uniform row
    int c = (int)(p & 1023);

    const f32x2* zr = (const f32x2*)(Zrow + r * 64);       // uniform -> scalar loads
    const f32x2* zc = (const f32x2*)(Zcol + (long)c * 64);

    // layer 1: h[j] = sin(30*(Zrow[r][j] + Zcol[c][j])) -- h lives in VGPRs
    f32x2 h[32];
    #pragma unroll
    for (int q = 0; q < 32; ++q) {
        f32x2 a = zr[q];
        f32x2 b = zc[q];
        h[q].x = __sinf(30.f * (a.x + b.x));
        h[q].y = __sinf(30.f * (a.y + b.y));
    }

    // layer 2 + head: w += W3[i]*sin(30*(W2[i,:] . h + b2[i]))
    // f32x2 accumulators -> v_pk_fma_f32 (packed fp32, 2 FMA/instr)
    float w = b3[0];
    for (int i = 0; i < 64; ++i) {
        const f32x2* w2r = (const f32x2*)(W2 + i * 64);     // wave-uniform
        f32x2 z0 = {b2[i], 0.f};
        f32x2 z1 = {0.f, 0.f}, z2 = {0.f, 0.f}, z3 = {0.f, 0.f};
        #pragma unroll
        for (int q = 0; q < 8; ++q) {
            z0 += w2r[4*q + 0] * h[4*q + 0];
            z1 += w2r[4*q + 1] * h[4*q + 1];
            z2 += w2r[4*q + 2] * h[4*q + 2];
            z3 += w2r[4*q + 3] * h[4*q + 3];
        }
        f32x2 zz = (z0 + z1) + (z2 + z3);
        w += W3[i] * __sinf(30.f * (zz.x + zz.y));
    }
    Wout[p] = f2bf(w);
}

// ---------------- stage B: out = x @ W^T + bias (bf16 MFMA) ----------------
// A = x_bf16 [8192][1024] K-contig; B = W_bf16 [1024][1024] (n=r, k=c) K-contig.
// Block: 256 thr = 4 waves (2x2 of 64x64), tile 128x128, BK=32.
// LDS chunk swizzle: row r (64B = 4 x 16B chunks), stored chunk p holds logical
// chunk p ^ ((r>>1)&3); staging lane fetches the matching global chunk.
__global__ __launch_bounds__(256) void gemm_kernel(
        const unsigned short* __restrict__ A,
        const unsigned short* __restrict__ B,
        const float* __restrict__ bias,
        float* __restrict__ C) {
    const int K = 1024;
    __shared__ __align__(16) unsigned short As[128 * 32];
    __shared__ __align__(16) unsigned short Bs[128 * 32];

    int tid  = threadIdx.x;
    int lane = tid & 63;
    int wv   = tid >> 6;
    int wm   = wv & 1, wn = wv >> 1;
    long Abase = (long)blockIdx.x * 128 * K;
    long Bbase = (long)blockIdx.y * 128 * K;

    int sr = tid >> 2;      // staging row 0..63 (+64 on round q=1)
    int sc = tid & 3;       // staging chunk slot
    int rsel = lane & 15;   // fragment row/col within 16
    int csel = lane >> 4;   // fragment k-chunk 0..3

    f32x4 acc[4][4] = {};

    for (int kt = 0; kt < K; kt += 32) {
        #pragma unroll
        for (int q = 0; q < 2; ++q) {
            int row = q * 64 + sr;
            int cc  = sc ^ ((row >> 1) & 3);                 // global chunk to fetch
            const unsigned short* ga = A + Abase + (long)row * K + kt + cc * 8;
            const unsigned short* gb = B + Bbase + (long)row * K + kt + cc * 8;
            unsigned short* la = &As[(q * 256 + wv * 64) * 8];  // wave-uniform base
            unsigned short* lb = &Bs[(q * 256 + wv * 64) * 8];
            async_ld16(ga, la);
            async_ld16(gb, lb);
        }
        __syncthreads();

        bf16x8 af[4], bf[4];
        #pragma unroll
        for (int mi = 0; mi < 4; ++mi) {
            int row = wm * 64 + mi * 16 + rsel;
            int ch  = csel ^ ((row >> 1) & 3);
            af[mi] = *(const bf16x8*)&As[row * 32 + ch * 8];
        }
        #pragma unroll
        for (int ni = 0; ni < 4; ++ni) {
            int row = wn * 64 + ni * 16 + rsel;
            int ch  = csel ^ ((row >> 1) & 3);
            bf[ni] = *(const bf16x8*)&Bs[row * 32 + ch * 8];
        }
        #pragma unroll
        for (int mi = 0; mi < 4; ++mi)
            #pragma unroll
            for (int ni = 0; ni < 4; ++ni)
                acc[mi][ni] = __builtin_amdgcn_mfma_f32_16x16x32_bf16(
                    af[mi], bf[ni], acc[mi][ni], 0, 0, 0);
        __syncthreads();
    }

    // epilogue: C/D layout col=lane&15, row=(lane>>4)*4+reg  (m89/m91 verified)
    int row0 = blockIdx.x * 128 + wm * 64;
    int col0 = blockIdx.y * 128 + wn * 64;
    #pragma unroll
    for (int ni = 0; ni < 4; ++ni) {
        int col = col0 + ni * 16 + rsel;
        float bv = bias[col];
        #pragma unroll
        for (int mi = 0; mi < 4; ++mi) {
            int rbase = row0 + mi * 16 + csel * 4;
            #pragma unroll
            for (int r = 0; r < 4; ++r)
                C[(long)(rbase + r) * 1024 + col] = acc[mi][ni][r] + bv;
        }
    }
}

extern "C" void kernel_launch(void* const* d_in, const int* in_sizes, int n_in,
                              void* d_out, int out_size, void* d_ws, size_t ws_size,
                              hipStream_t stream) {
    const float* x    = (const float*)d_in[0];
    const float* ec   = (const float*)d_in[1];
    const float* W1   = (const float*)d_in[2];
    const float* b1   = (const float*)d_in[3];
    const float* W2   = (const float*)d_in[4];
    const float* b2   = (const float*)d_in[5];
    const float* W3   = (const float*)d_in[6];
    const float* b3   = (const float*)d_in[7];
    const float* bias = (const float*)d_in[8];
    float* out = (float*)d_out;

    unsigned short* xb = (unsigned short*)d_ws;            // 8192*1024 bf16 = 16 MB
    unsigned short* Wb = xb + (size_t)8192 * 1024;         // 1024*1024 bf16 = 2 MB
    float* Zrow = (float*)(Wb + (size_t)1024 * 1024);      // 1024*64 f32 = 256 KB
    float* Zcol = Zrow + 1024 * 64;                        // 1024*64 f32 = 256 KB

    cast_x_kernel<<<8192, 256, 0, stream>>>((const float4*)x, xb);
    siren_tables_kernel<<<8, 256, 0, stream>>>(ec, W1, b1, Zrow, Zcol);
    siren_w_kernel<<<4096, 256, 0, stream>>>(Zrow, Zcol, W2, b2, W3, b3, Wb);
    dim3 g(64, 8);
    gemm_kernel<<<g, 256, 0, stream>>>(xb, Wb, bias, out);
}

// Round 4
// 225.233 us; speedup vs baseline: 1.6835x; 1.2523x over previous
//
#include <hip/hip_runtime.h>
#include <hip/hip_bf16.h>

// SirenLinear: out[b,r] = sum_c x[b,c] * W[r,c] + bias[r]
//   W[r,c] = b3 + h2 . W3,  h2 = sin(30*(W2 h1 + b2)),  h1 = sin(30*(W1 e + b1))
//
// Layer 1 is exactly separable: z1(r,c) = Zrow[r] + Zcol[c]  (0.5 MB tables).
// Layer 2 is a [1M x 64] @ [64 x 64] GEMM -> MFMA (round 1-3 lesson: keeping
// all 64 h-values per lane forces an AGPR spill at any launch_bounds; the
// VALU pipe was burning ~4k instr/point. MFMA does it in 8 instr/16 points).
// Per wave: 16-point tile; lane builds A-frag (m=lane&15 point, k=(lane>>4)*8+j)
// from sin(30*(Zrow+Zcol)); W2 lives in 8 preloaded B-frags; epilogue does
// sin + W3-dot + 16-lane shfl reduction + ushort4 store.

typedef __attribute__((ext_vector_type(8))) short bf16x8;
typedef __attribute__((ext_vector_type(4))) float f32x4;

__device__ __forceinline__ unsigned short f2bf(float f) {
    union { float f; unsigned u; } v; v.f = f;
    unsigned r = v.u + 0x7fffu + ((v.u >> 16) & 1u);   // RNE
    return (unsigned short)(r >> 16);
}

__device__ __forceinline__ void async_ld16(const void* g, void* l) {
    __builtin_amdgcn_global_load_lds(
        (__attribute__((address_space(1))) void*)g,
        (__attribute__((address_space(3))) void*)l, 16, 0, 0);
}

// ---------------- cast x fp32 -> bf16 ----------------
__global__ __launch_bounds__(256) void cast_x_kernel(
        const float4* __restrict__ x, unsigned short* __restrict__ xb) {
    long i = (long)blockIdx.x * 256 + threadIdx.x;   // one float4 per thread
    float4 v = x[i];
    ushort4 o;
    o.x = f2bf(v.x); o.y = f2bf(v.y); o.z = f2bf(v.z); o.w = f2bf(v.w);
    *(ushort4*)(xb + i * 4) = o;
}

// ---------------- stage A0: layer-1 separability tables ----------------
// Zrow[r][j] = W1[j,:] . e(r,0) + b1[j]
// Zcol[c][j] = W1[j,:] . (e(0,c) - e(0,0))      (y-components cancel exactly)
__global__ __launch_bounds__(256) void siren_tables_kernel(
        const float* __restrict__ ec,
        const float* __restrict__ W1, const float* __restrict__ b1,
        float* __restrict__ Zrow, float* __restrict__ Zcol) {
    int t = blockIdx.x * 256 + threadIdx.x;          // 0..2047
    float e[18];
    if (t < 1024) {
        const float* pe = ec + (long)t * 1024 * 18;  // point (r=t, c=0)
        #pragma unroll
        for (int i = 0; i < 18; ++i) e[i] = pe[i];
        for (int j = 0; j < 64; ++j) {
            float z = b1[j];
            #pragma unroll
            for (int i = 0; i < 18; ++i) z += W1[j * 18 + i] * e[i];
            Zrow[t * 64 + j] = z;
        }
    } else {
        int c = t - 1024;
        const float* pe = ec + (long)c * 18;         // point (r=0, c)
        #pragma unroll
        for (int i = 0; i < 18; ++i) e[i] = pe[i] - ec[i];
        for (int j = 0; j < 64; ++j) {
            float z = 0.f;
            #pragma unroll
            for (int i = 0; i < 18; ++i) z += W1[j * 18 + i] * e[i];
            Zcol[c * 64 + j] = z;
        }
    }
}

// ---------------- stage A: generate W (bf16) via MFMA ----------------
__global__ __launch_bounds__(256, 4) void siren_w_kernel(
        const float* __restrict__ Zrow, const float* __restrict__ Zcol,
        const float* __restrict__ W2, const float* __restrict__ b2,
        const float* __restrict__ W3, const float* __restrict__ b3,
        unsigned short* __restrict__ Wout) {
    int lane = threadIdx.x & 63;
    int wv   = threadIdx.x >> 6;
    int ln   = lane & 15;    // A: point within tile; B: n within n-tile
    int kq   = lane >> 4;    // k-quad (elements k = kq*8 + j)

    // Preload B-fragments of W2 (bf16): bfrag[kc][nt][j] = W2[n][k],
    // n = nt*16+ln, k = kc*32 + kq*8 + j   (W2 row-major [n][k], k contig)
    bf16x8 bfrag[2][4];
    #pragma unroll
    for (int kc = 0; kc < 2; ++kc)
        #pragma unroll
        for (int nt = 0; nt < 4; ++nt) {
            const float* src = W2 + (nt * 16 + ln) * 64 + kc * 32 + kq * 8;
            union { bf16x8 v; unsigned short u[8]; } tmp;
            #pragma unroll
            for (int j = 0; j < 8; ++j) tmp.u[j] = f2bf(src[j]);
            bfrag[kc][nt] = tmp.v;
        }
    float b2v[4], w3v[4];
    #pragma unroll
    for (int nt = 0; nt < 4; ++nt) {
        b2v[nt] = b2[nt * 16 + ln];
        w3v[nt] = W3[nt * 16 + ln];
    }
    float b3s = b3[0];

    // 65536 tiles of 16 points; 4096 waves x 16 consecutive tiles each
    long wave_id = (long)blockIdx.x * 4 + wv;
    for (int it = 0; it < 16; ++it) {
        long tile = wave_id * 16 + it;
        long p0 = tile * 16;
        int r = (int)(p0 >> 10);               // tile never crosses a row (1024%16==0)
        int c = (int)(p0 & 1023) + ln;         // this lane's point column

        // A-fragments: h1[point p0+ln][k], k = kc*32 + kq*8 + j
        const float* zc = Zcol + (long)c * 64 + kq * 8;
        const float* zr = Zrow + (long)r * 64 + kq * 8;
        union { bf16x8 v; unsigned short u[8]; } a0, a1;
        #pragma unroll
        for (int j = 0; j < 8; ++j) {
            a0.u[j] = f2bf(__sinf(30.f * (zr[j] + zc[j])));
            a1.u[j] = f2bf(__sinf(30.f * (zr[32 + j] + zc[32 + j])));
        }

        f32x4 acc[4] = {};
        #pragma unroll
        for (int nt = 0; nt < 4; ++nt) {
            acc[nt] = __builtin_amdgcn_mfma_f32_16x16x32_bf16(a0.v, bfrag[0][nt], acc[nt], 0, 0, 0);
            acc[nt] = __builtin_amdgcn_mfma_f32_16x16x32_bf16(a1.v, bfrag[1][nt], acc[nt], 0, 0, 0);
        }

        // head: C/D layout col=lane&15 (=n), row=kq*4+rg (=point within tile)
        float part[4];
        #pragma unroll
        for (int rg = 0; rg < 4; ++rg) {
            float s = 0.f;
            #pragma unroll
            for (int nt = 0; nt < 4; ++nt)
                s += w3v[nt] * __sinf(30.f * (acc[nt][rg] + b2v[nt]));
            part[rg] = s;
        }
        // reduce over the 16 col-lanes (xor 1,2,4,8 stays in 32-lane groups)
        #pragma unroll
        for (int m = 1; m < 16; m <<= 1)
            #pragma unroll
            for (int rg = 0; rg < 4; ++rg)
                part[rg] += __shfl_xor(part[rg], m, 64);

        if (ln == 0) {                          // 4 lanes store 4 points each
            ushort4 o;
            o.x = f2bf(part[0] + b3s);
            o.y = f2bf(part[1] + b3s);
            o.z = f2bf(part[2] + b3s);
            o.w = f2bf(part[3] + b3s);
            *(ushort4*)(Wout + p0 + kq * 4) = o;
        }
    }
}

// ---------------- stage B: out = x @ W^T + bias (bf16 MFMA) ----------------
// A = x_bf16 [8192][1024] K-contig; B = W_bf16 [1024][1024] (n=r, k=c) K-contig.
// Block: 256 thr = 4 waves (2x2 of 64x64), tile 128x128, BK=32.
// LDS chunk swizzle: row r (64B = 4 x 16B chunks), stored chunk p holds logical
// chunk p ^ ((r>>1)&3); staging lane fetches the matching global chunk.
__global__ __launch_bounds__(256) void gemm_kernel(
        const unsigned short* __restrict__ A,
        const unsigned short* __restrict__ B,
        const float* __restrict__ bias,
        float* __restrict__ C) {
    const int K = 1024;
    __shared__ __align__(16) unsigned short As[128 * 32];
    __shared__ __align__(16) unsigned short Bs[128 * 32];

    int tid  = threadIdx.x;
    int lane = tid & 63;
    int wv   = tid >> 6;
    int wm   = wv & 1, wn = wv >> 1;
    long Abase = (long)blockIdx.x * 128 * K;
    long Bbase = (long)blockIdx.y * 128 * K;

    int sr = tid >> 2;      // staging row 0..63 (+64 on round q=1)
    int sc = tid & 3;       // staging chunk slot
    int rsel = lane & 15;   // fragment row/col within 16
    int csel = lane >> 4;   // fragment k-chunk 0..3

    f32x4 acc[4][4] = {};

    for (int kt = 0; kt < K; kt += 32) {
        #pragma unroll
        for (int q = 0; q < 2; ++q) {
            int row = q * 64 + sr;
            int cc  = sc ^ ((row >> 1) & 3);                 // global chunk to fetch
            const unsigned short* ga = A + Abase + (long)row * K + kt + cc * 8;
            const unsigned short* gb = B + Bbase + (long)row * K + kt + cc * 8;
            unsigned short* la = &As[(q * 256 + wv * 64) * 8];  // wave-uniform base
            unsigned short* lb = &Bs[(q * 256 + wv * 64) * 8];
            async_ld16(ga, la);
            async_ld16(gb, lb);
        }
        __syncthreads();

        bf16x8 af[4], bf[4];
        #pragma unroll
        for (int mi = 0; mi < 4; ++mi) {
            int row = wm * 64 + mi * 16 + rsel;
            int ch  = csel ^ ((row >> 1) & 3);
            af[mi] = *(const bf16x8*)&As[row * 32 + ch * 8];
        }
        #pragma unroll
        for (int ni = 0; ni < 4; ++ni) {
            int row = wn * 64 + ni * 16 + rsel;
            int ch  = csel ^ ((row >> 1) & 3);
            bf[ni] = *(const bf16x8*)&Bs[row * 32 + ch * 8];
        }
        #pragma unroll
        for (int mi = 0; mi < 4; ++mi)
            #pragma unroll
            for (int ni = 0; ni < 4; ++ni)
                acc[mi][ni] = __builtin_amdgcn_mfma_f32_16x16x32_bf16(
                    af[mi], bf[ni], acc[mi][ni], 0, 0, 0);
        __syncthreads();
    }

    // epilogue: C/D layout col=lane&15, row=(lane>>4)*4+reg  (m89/m91 verified)
    int row0 = blockIdx.x * 128 + wm * 64;
    int col0 = blockIdx.y * 128 + wn * 64;
    #pragma unroll
    for (int ni = 0; ni < 4; ++ni) {
        int col = col0 + ni * 16 + rsel;
        float bv = bias[col];
        #pragma unroll
        for (int mi = 0; mi < 4; ++mi) {
            int rbase = row0 + mi * 16 + csel * 4;
            #pragma unroll
            for (int r = 0; r < 4; ++r)
                C[(long)(rbase + r) * 1024 + col] = acc[mi][ni][r] + bv;
        }
    }
}

extern "C" void kernel_launch(void* const* d_in, const int* in_sizes, int n_in,
                              void* d_out, int out_size, void* d_ws, size_t ws_size,
                              hipStream_t stream) {
    const float* x    = (const float*)d_in[0];
    const float* ec   = (const float*)d_in[1];
    const float* W1   = (const float*)d_in[2];
    const float* b1   = (const float*)d_in[3];
    const float* W2   = (const float*)d_in[4];
    const float* b2   = (const float*)d_in[5];
    const float* W3   = (const float*)d_in[6];
    const float* b3   = (const float*)d_in[7];
    const float* bias = (const float*)d_in[8];
    float* out = (float*)d_out;

    unsigned short* xb = (unsigned short*)d_ws;            // 8192*1024 bf16 = 16 MB
    unsigned short* Wb = xb + (size_t)8192 * 1024;         // 1024*1024 bf16 = 2 MB
    float* Zrow = (float*)(Wb + (size_t)1024 * 1024);      // 1024*64 f32 = 256 KB
    float* Zcol = Zrow + 1024 * 64;                        // 1024*64 f32 = 256 KB

    cast_x_kernel<<<8192, 256, 0, stream>>>((const float4*)x, xb);
    siren_tables_kernel<<<8, 256, 0, stream>>>(ec, W1, b1, Zrow, Zcol);
    siren_w_kernel<<<1024, 256, 0, stream>>>(Zrow, Zcol, W2, b2, W3, b3, Wb);
    dim3 g(64, 8);
    gemm_kernel<<<g, 256, 0, stream>>>(xb, Wb, bias, out);
}

// Round 5
// 215.626 us; speedup vs baseline: 1.7585x; 1.0446x over previous
//
#include <hip/hip_runtime.h>
#include <hip/hip_bf16.h>

// SirenLinear: out[b,r] = sum_c x[b,c] * W[r,c] + bias[r]
//   W[r,c] = b3 + h2 . W3,  h2 = sin(30*(W2 h1 + b2)),  h1 = sin(30*(W1 e + b1))
//
// Layer 1 exactly separable: 30*z1(r,c) = Zrow[r] + Zcol[c] (tables pre-scaled
// by 30; 0.5 MB). Layer 2 = [1M x 64] @ [64 x 64] GEMM -> MFMA per 16-pt tile.
// Round-4 lessons: occupancy 34% (grid too small) + VALU fat (RNE cvt 5 instr,
// explicit 30* muls). Round 5: grid 2048x4 waves (32 waves/CU demand), fold 30
// into tables/W2/b2, truncation-pack bf16 for MFMA inputs (1 instr/pair; RNE
// kept for final W store), hoist wave-invariant Zrow loads.

typedef __attribute__((ext_vector_type(8))) short bf16x8;
typedef __attribute__((ext_vector_type(4))) float f32x4;

__device__ __forceinline__ unsigned short f2bf(float f) {
    union { float f; unsigned u; } v; v.f = f;
    unsigned r = v.u + 0x7fffu + ((v.u >> 16) & 1u);   // RNE
    return (unsigned short)(r >> 16);
}

// pack 2 floats -> 2 bf16 by truncation (1-2 instr; ~0.4% worst-case vs RNE)
__device__ __forceinline__ unsigned pktrunc(float a, float b) {
    union { float f; unsigned u; } x, y; x.f = a; y.f = b;
    return (x.u >> 16) | (y.u & 0xffff0000u);
}

__device__ __forceinline__ void async_ld16(const void* g, void* l) {
    __builtin_amdgcn_global_load_lds(
        (__attribute__((address_space(1))) void*)g,
        (__attribute__((address_space(3))) void*)l, 16, 0, 0);
}

// ---------------- cast x fp32 -> bf16 ----------------
__global__ __launch_bounds__(256) void cast_x_kernel(
        const float4* __restrict__ x, unsigned short* __restrict__ xb) {
    long i = (long)blockIdx.x * 256 + threadIdx.x;   // one float4 per thread
    float4 v = x[i];
    ushort4 o;
    o.x = f2bf(v.x); o.y = f2bf(v.y); o.z = f2bf(v.z); o.w = f2bf(v.w);
    *(ushort4*)(xb + i * 4) = o;
}

// ---------------- stage A0: layer-1 separability tables (pre-scaled by 30) --
// Zrow[r][j] = 30*(W1[j,:] . e(r,0) + b1[j])
// Zcol[c][j] = 30*(W1[j,:] . (e(0,c) - e(0,0)))   (y-components cancel exactly)
// thread per (t,j): 2048*64 = 128K threads.
__global__ __launch_bounds__(256) void siren_tables_kernel(
        const float* __restrict__ ec,
        const float* __restrict__ W1, const float* __restrict__ b1,
        float* __restrict__ Zrow, float* __restrict__ Zcol) {
    int idx = blockIdx.x * 256 + threadIdx.x;        // 0..131071
    int j = idx & 63;
    int t = idx >> 6;                                // 0..2047
    const float* wr = W1 + j * 18;
    if (t < 1024) {
        const float* pe = ec + (long)t * 1024 * 18;  // point (r=t, c=0)
        float z = b1[j];
        #pragma unroll
        for (int i = 0; i < 18; ++i) z += wr[i] * pe[i];
        Zrow[t * 64 + j] = 30.f * z;
    } else {
        int c = t - 1024;
        const float* pe = ec + (long)c * 18;         // point (r=0, c)
        float z = 0.f;
        #pragma unroll
        for (int i = 0; i < 18; ++i) z += wr[i] * (pe[i] - ec[i]);
        Zcol[c * 64 + j] = 30.f * z;
    }
}

// ---------------- stage A: generate W (bf16) via MFMA ----------------
// Wave covers 128 consecutive points of one row (8 tiles of 16).
// A-frag: m=ln (point), k=kq*8+j (+32 for a1). B-frag: n=nt*16+ln, same k.
// C/D: col=ln (=n), row=kq*4+rg (=point) [m89/m91 layouts].
__global__ __launch_bounds__(256, 4) void siren_w_kernel(
        const float* __restrict__ Zrow, const float* __restrict__ Zcol,
        const float* __restrict__ W2, const float* __restrict__ b2,
        const float* __restrict__ W3, const float* __restrict__ b3,
        unsigned short* __restrict__ Wout) {
    int lane = threadIdx.x & 63;
    int wv   = threadIdx.x >> 6;
    int ln   = lane & 15;
    int kq   = lane >> 4;

    // Preload B-frags of 30*W2 (trunc bf16), 30*b2, W3
    bf16x8 bfrag[2][4];
    #pragma unroll
    for (int kc = 0; kc < 2; ++kc)
        #pragma unroll
        for (int nt = 0; nt < 4; ++nt) {
            const float* src = W2 + (nt * 16 + ln) * 64 + kc * 32 + kq * 8;
            union { bf16x8 v; unsigned u[4]; } tmp;
            #pragma unroll
            for (int q = 0; q < 4; ++q)
                tmp.u[q] = pktrunc(30.f * src[2*q], 30.f * src[2*q + 1]);
            bfrag[kc][nt] = tmp.v;
        }
    float b2v[4], w3v[4];
    #pragma unroll
    for (int nt = 0; nt < 4; ++nt) {
        b2v[nt] = 30.f * b2[nt * 16 + ln];
        w3v[nt] = W3[nt * 16 + ln];
    }
    float b3s = b3[0];

    int wid = blockIdx.x * 4 + wv;          // 0..8191 waves
    int r   = wid >> 3;                     // 8 waves per row
    int c0  = (wid & 7) * 128;

    // wave-invariant Zrow fragment (k = kq*8+j and 32+kq*8+j)
    const float* zrp = Zrow + (long)r * 64 + kq * 8;
    float zr0[8], zr1[8];
    #pragma unroll
    for (int j = 0; j < 8; ++j) { zr0[j] = zrp[j]; zr1[j] = zrp[32 + j]; }

    for (int it = 0; it < 8; ++it) {
        int c = c0 + it * 16 + ln;
        const float* zc = Zcol + (long)c * 64 + kq * 8;

        float s0[8], s1[8];
        #pragma unroll
        for (int j = 0; j < 8; ++j) {
            s0[j] = __sinf(zr0[j] + zc[j]);
            s1[j] = __sinf(zr1[j] + zc[32 + j]);
        }
        union { bf16x8 v; unsigned u[4]; } a0, a1;
        #pragma unroll
        for (int q = 0; q < 4; ++q) {
            a0.u[q] = pktrunc(s0[2*q], s0[2*q + 1]);
            a1.u[q] = pktrunc(s1[2*q], s1[2*q + 1]);
        }

        f32x4 acc[4] = {};
        #pragma unroll
        for (int nt = 0; nt < 4; ++nt) {
            acc[nt] = __builtin_amdgcn_mfma_f32_16x16x32_bf16(a0.v, bfrag[0][nt], acc[nt], 0, 0, 0);
            acc[nt] = __builtin_amdgcn_mfma_f32_16x16x32_bf16(a1.v, bfrag[1][nt], acc[nt], 0, 0, 0);
        }

        float part[4];
        #pragma unroll
        for (int rg = 0; rg < 4; ++rg) {
            float s = 0.f;
            #pragma unroll
            for (int nt = 0; nt < 4; ++nt)
                s += w3v[nt] * __sinf(acc[nt][rg] + b2v[nt]);
            part[rg] = s;
        }
        #pragma unroll
        for (int m = 1; m < 16; m <<= 1)
            #pragma unroll
            for (int rg = 0; rg < 4; ++rg)
                part[rg] += __shfl_xor(part[rg], m, 64);

        if (ln == 0) {                       // 4 lanes store 4 points each (RNE)
            long p0 = (long)r * 1024 + c0 + it * 16;
            ushort4 o;
            o.x = f2bf(part[0] + b3s);
            o.y = f2bf(part[1] + b3s);
            o.z = f2bf(part[2] + b3s);
            o.w = f2bf(part[3] + b3s);
            *(ushort4*)(Wout + p0 + kq * 4) = o;
        }
    }
}

// ---------------- stage B: out = x @ W^T + bias (bf16 MFMA) ----------------
// A = x_bf16 [8192][1024] K-contig; B = W_bf16 [1024][1024] (n=r, k=c) K-contig.
// Block: 256 thr = 4 waves (2x2 of 64x64), tile 128x128, BK=32.
// LDS chunk swizzle: row r (64B = 4 x 16B chunks), stored chunk p holds logical
// chunk p ^ ((r>>1)&3); staging lane fetches the matching global chunk.
__global__ __launch_bounds__(256) void gemm_kernel(
        const unsigned short* __restrict__ A,
        const unsigned short* __restrict__ B,
        const float* __restrict__ bias,
        float* __restrict__ C) {
    const int K = 1024;
    __shared__ __align__(16) unsigned short As[128 * 32];
    __shared__ __align__(16) unsigned short Bs[128 * 32];

    int tid  = threadIdx.x;
    int lane = tid & 63;
    int wv   = tid >> 6;
    int wm   = wv & 1, wn = wv >> 1;
    long Abase = (long)blockIdx.x * 128 * K;
    long Bbase = (long)blockIdx.y * 128 * K;

    int sr = tid >> 2;      // staging row 0..63 (+64 on round q=1)
    int sc = tid & 3;       // staging chunk slot
    int rsel = lane & 15;   // fragment row/col within 16
    int csel = lane >> 4;   // fragment k-chunk 0..3

    f32x4 acc[4][4] = {};

    for (int kt = 0; kt < K; kt += 32) {
        #pragma unroll
        for (int q = 0; q < 2; ++q) {
            int row = q * 64 + sr;
            int cc  = sc ^ ((row >> 1) & 3);                 // global chunk to fetch
            const unsigned short* ga = A + Abase + (long)row * K + kt + cc * 8;
            const unsigned short* gb = B + Bbase + (long)row * K + kt + cc * 8;
            unsigned short* la = &As[(q * 256 + wv * 64) * 8];  // wave-uniform base
            unsigned short* lb = &Bs[(q * 256 + wv * 64) * 8];
            async_ld16(ga, la);
            async_ld16(gb, lb);
        }
        __syncthreads();

        bf16x8 af[4], bf[4];
        #pragma unroll
        for (int mi = 0; mi < 4; ++mi) {
            int row = wm * 64 + mi * 16 + rsel;
            int ch  = csel ^ ((row >> 1) & 3);
            af[mi] = *(const bf16x8*)&As[row * 32 + ch * 8];
        }
        #pragma unroll
        for (int ni = 0; ni < 4; ++ni) {
            int row = wn * 64 + ni * 16 + rsel;
            int ch  = csel ^ ((row >> 1) & 3);
            bf[ni] = *(const bf16x8*)&Bs[row * 32 + ch * 8];
        }
        #pragma unroll
        for (int mi = 0; mi < 4; ++mi)
            #pragma unroll
            for (int ni = 0; ni < 4; ++ni)
                acc[mi][ni] = __builtin_amdgcn_mfma_f32_16x16x32_bf16(
                    af[mi], bf[ni], acc[mi][ni], 0, 0, 0);
        __syncthreads();
    }

    // epilogue: C/D layout col=lane&15, row=(lane>>4)*4+reg  (m89/m91 verified)
    int row0 = blockIdx.x * 128 + wm * 64;
    int col0 = blockIdx.y * 128 + wn * 64;
    #pragma unroll
    for (int ni = 0; ni < 4; ++ni) {
        int col = col0 + ni * 16 + rsel;
        float bv = bias[col];
        #pragma unroll
        for (int mi = 0; mi < 4; ++mi) {
            int rbase = row0 + mi * 16 + csel * 4;
            #pragma unroll
            for (int r = 0; r < 4; ++r)
                C[(long)(rbase + r) * 1024 + col] = acc[mi][ni][r] + bv;
        }
    }
}

extern "C" void kernel_launch(void* const* d_in, const int* in_sizes, int n_in,
                              void* d_out, int out_size, void* d_ws, size_t ws_size,
                              hipStream_t stream) {
    const float* x    = (const float*)d_in[0];
    const float* ec   = (const float*)d_in[1];
    const float* W1   = (const float*)d_in[2];
    const float* b1   = (const float*)d_in[3];
    const float* W2   = (const float*)d_in[4];
    const float* b2   = (const float*)d_in[5];
    const float* W3   = (const float*)d_in[6];
    const float* b3   = (const float*)d_in[7];
    const float* bias = (const float*)d_in[8];
    float* out = (float*)d_out;

    unsigned short* xb = (unsigned short*)d_ws;            // 8192*1024 bf16 = 16 MB
    unsigned short* Wb = xb + (size_t)8192 * 1024;         // 1024*1024 bf16 = 2 MB
    float* Zrow = (float*)(Wb + (size_t)1024 * 1024);      // 1024*64 f32 = 256 KB
    float* Zcol = Zrow + 1024 * 64;                        // 1024*64 f32 = 256 KB

    cast_x_kernel<<<8192, 256, 0, stream>>>((const float4*)x, xb);
    siren_tables_kernel<<<512, 256, 0, stream>>>(ec, W1, b1, Zrow, Zcol);
    siren_w_kernel<<<2048, 256, 0, stream>>>(Zrow, Zcol, W2, b2, W3, b3, Wb);
    dim3 g(64, 8);
    gemm_kernel<<<g, 256, 0, stream>>>(xb, Wb, bias, out);
}

// Round 6
// 209.582 us; speedup vs baseline: 1.8092x; 1.0288x over previous
//
#include <hip/hip_runtime.h>
#include <hip/hip_bf16.h>

// SirenLinear: out[b,r] = sum_c x[b,c] * W[r,c] + bias[r]
//   W[r,c] = b3 + h2 . W3,  h2 = sin(30*(W2 h1 + b2)),  h1 = sin(30*(W1 e + b1))
//
// Layer 1 exactly separable: z1(r,c) = Zrow[r] + Zcol[c]. Tables, W2, b2 are
// pre-scaled by 30/(2*pi) so every sine is ONE raw v_sin_f32 (revolutions).
// Layer 2 = [1M x 64] @ [64 x 64] GEMM -> MFMA per 16-pt tile.
// Round-5 lessons: residency caps at ~3-4 waves/SIMD (register-total), so
// (a) fewer/longer waves amortize the W2-fragment preload, (b) 2 tiles
// interleaved per iteration give 2 independent chains to hide latency,
// (c) ds_swizzle (1 instr) replaces shfl_xor addr-setup in the reduction.

typedef __attribute__((ext_vector_type(8))) short bf16x8;
typedef __attribute__((ext_vector_type(4))) float f32x4;

#define SIN_SCALE 4.77464829275686f   // 30 / (2*pi)

__device__ __forceinline__ unsigned short f2bf(float f) {
    union { float f; unsigned u; } v; v.f = f;
    unsigned r = v.u + 0x7fffu + ((v.u >> 16) & 1u);   // RNE
    return (unsigned short)(r >> 16);
}

// pack 2 floats -> 2 bf16 by truncation (cheap; RNE kept for final store)
__device__ __forceinline__ unsigned pktrunc(float a, float b) {
    union { float f; unsigned u; } x, y; x.f = a; y.f = b;
    return (x.u >> 16) | (y.u & 0xffff0000u);
}

// sin(2*pi*x) -- raw v_sin_f32, valid |x| <= 256 revs (here |x| <= ~8.3)
__device__ __forceinline__ float sinrev(float x) {
    return __builtin_amdgcn_sinf(x);
}

// butterfly add over lane^m (bitmode ds_swizzle, m in {1,2,4,8})
template <int OFF>
__device__ __forceinline__ float swz_add(float v) {
    return v + __int_as_float(__builtin_amdgcn_ds_swizzle(__float_as_int(v), OFF));
}

__device__ __forceinline__ void async_ld16(const void* g, void* l) {
    __builtin_amdgcn_global_load_lds(
        (__attribute__((address_space(1))) void*)g,
        (__attribute__((address_space(3))) void*)l, 16, 0, 0);
}

// ---------------- cast x fp32 -> bf16 ----------------
__global__ __launch_bounds__(256) void cast_x_kernel(
        const float4* __restrict__ x, unsigned short* __restrict__ xb) {
    long i = (long)blockIdx.x * 256 + threadIdx.x;   // one float4 per thread
    float4 v = x[i];
    ushort4 o;
    o.x = f2bf(v.x); o.y = f2bf(v.y); o.z = f2bf(v.z); o.w = f2bf(v.w);
    *(ushort4*)(xb + i * 4) = o;
}

// ---------------- stage A0: layer-1 tables, pre-scaled by 30/(2pi) ---------
// Zrow[r][j] = S*(W1[j,:] . e(r,0) + b1[j])
// Zcol[c][j] = S*(W1[j,:] . (e(0,c) - e(0,0)))   (y-components cancel exactly)
__global__ __launch_bounds__(256) void siren_tables_kernel(
        const float* __restrict__ ec,
        const float* __restrict__ W1, const float* __restrict__ b1,
        float* __restrict__ Zrow, float* __restrict__ Zcol) {
    int idx = blockIdx.x * 256 + threadIdx.x;        // 0..131071
    int j = idx & 63;
    int t = idx >> 6;                                // 0..2047
    const float* wr = W1 + j * 18;
    if (t < 1024) {
        const float* pe = ec + (long)t * 1024 * 18;  // point (r=t, c=0)
        float z = b1[j];
        #pragma unroll
        for (int i = 0; i < 18; ++i) z += wr[i] * pe[i];
        Zrow[t * 64 + j] = SIN_SCALE * z;
    } else {
        int c = t - 1024;
        const float* pe = ec + (long)c * 18;         // point (r=0, c)
        float z = 0.f;
        #pragma unroll
        for (int i = 0; i < 18; ++i) z += wr[i] * (pe[i] - ec[i]);
        Zcol[c * 64 + j] = SIN_SCALE * z;
    }
}

// ---------------- stage A: generate W (bf16) via MFMA ----------------
// Wave covers 256 consecutive points of one row: 8 iters x 2 interleaved
// 16-pt tiles. A-frag: m=ln (point), k=kq*8+j (+32 for *1). B-frag: n=nt*16+ln.
// C/D: col=ln (=n), row=kq*4+rg (=point) [m89/m91 layouts].
__global__ __launch_bounds__(256, 3) void siren_w_kernel(
        const float* __restrict__ Zrow, const float* __restrict__ Zcol,
        const float* __restrict__ W2, const float* __restrict__ b2,
        const float* __restrict__ W3, const float* __restrict__ b3,
        unsigned short* __restrict__ Wout) {
    int lane = threadIdx.x & 63;
    int wv   = threadIdx.x >> 6;
    int ln   = lane & 15;
    int kq   = lane >> 4;

    // Preload B-frags of S*W2 (trunc bf16), S*b2, W3
    bf16x8 bfrag[2][4];
    #pragma unroll
    for (int kc = 0; kc < 2; ++kc)
        #pragma unroll
        for (int nt = 0; nt < 4; ++nt) {
            const float* src = W2 + (nt * 16 + ln) * 64 + kc * 32 + kq * 8;
            union { bf16x8 v; unsigned u[4]; } tmp;
            #pragma unroll
            for (int q = 0; q < 4; ++q)
                tmp.u[q] = pktrunc(SIN_SCALE * src[2*q], SIN_SCALE * src[2*q + 1]);
            bfrag[kc][nt] = tmp.v;
        }
    float b2v[4], w3v[4];
    #pragma unroll
    for (int nt = 0; nt < 4; ++nt) {
        b2v[nt] = SIN_SCALE * b2[nt * 16 + ln];
        w3v[nt] = W3[nt * 16 + ln];
    }
    float b3s = b3[0];

    int wid = blockIdx.x * 4 + wv;          // 0..4095 waves
    int r   = wid >> 2;                     // 4 waves per row
    int c0  = (wid & 3) * 256;

    // wave-invariant Zrow fragment (k = kq*8+j and 32+kq*8+j)
    const float* zrp = Zrow + (long)r * 64 + kq * 8;
    float zr0[8], zr1[8];
    #pragma unroll
    for (int j = 0; j < 8; ++j) { zr0[j] = zrp[j]; zr1[j] = zrp[32 + j]; }

    for (int it = 0; it < 8; ++it) {
        int ca = c0 + it * 32 + ln;                 // tile A point col
        const float* zca = Zcol + (long)ca * 64 + kq * 8;
        const float* zcb = zca + 16 * 64;           // tile B: +16 cols

        // h1 sins for both tiles (raw v_sin, args in revolutions)
        float sa0[8], sa1[8], sb0[8], sb1[8];
        #pragma unroll
        for (int j = 0; j < 8; ++j) {
            sa0[j] = sinrev(zr0[j] + zca[j]);
            sa1[j] = sinrev(zr1[j] + zca[32 + j]);
            sb0[j] = sinrev(zr0[j] + zcb[j]);
            sb1[j] = sinrev(zr1[j] + zcb[32 + j]);
        }
        union { bf16x8 v; unsigned u[4]; } a0, a1, bb0, bb1;
        #pragma unroll
        for (int q = 0; q < 4; ++q) {
            a0.u[q]  = pktrunc(sa0[2*q], sa0[2*q + 1]);
            a1.u[q]  = pktrunc(sa1[2*q], sa1[2*q + 1]);
            bb0.u[q] = pktrunc(sb0[2*q], sb0[2*q + 1]);
            bb1.u[q] = pktrunc(sb1[2*q], sb1[2*q + 1]);
        }

        f32x4 acca[4] = {}, accb[4] = {};
        #pragma unroll
        for (int nt = 0; nt < 4; ++nt) {
            acca[nt] = __builtin_amdgcn_mfma_f32_16x16x32_bf16(a0.v,  bfrag[0][nt], acca[nt], 0, 0, 0);
            accb[nt] = __builtin_amdgcn_mfma_f32_16x16x32_bf16(bb0.v, bfrag[0][nt], accb[nt], 0, 0, 0);
            acca[nt] = __builtin_amdgcn_mfma_f32_16x16x32_bf16(a1.v,  bfrag[1][nt], acca[nt], 0, 0, 0);
            accb[nt] = __builtin_amdgcn_mfma_f32_16x16x32_bf16(bb1.v, bfrag[1][nt], accb[nt], 0, 0, 0);
        }

        // head for both tiles: h2 = sin(acc + b2'), dot W3
        float pa[4], pb[4];
        #pragma unroll
        for (int rg = 0; rg < 4; ++rg) {
            float s = 0.f, t2 = 0.f;
            #pragma unroll
            for (int nt = 0; nt < 4; ++nt) {
                s  += w3v[nt] * sinrev(acca[nt][rg] + b2v[nt]);
                t2 += w3v[nt] * sinrev(accb[nt][rg] + b2v[nt]);
            }
            pa[rg] = s; pb[rg] = t2;
        }
        // reduce over the 16 col-lanes (two independent chains interleave)
        #pragma unroll
        for (int rg = 0; rg < 4; ++rg) {
            pa[rg] = swz_add<0x041F>(pa[rg]);  pb[rg] = swz_add<0x041F>(pb[rg]);
            pa[rg] = swz_add<0x081F>(pa[rg]);  pb[rg] = swz_add<0x081F>(pb[rg]);
            pa[rg] = swz_add<0x101F>(pa[rg]);  pb[rg] = swz_add<0x101F>(pb[rg]);
            pa[rg] = swz_add<0x201F>(pa[rg]);  pb[rg] = swz_add<0x201F>(pb[rg]);
        }

        if (ln == 0) {                       // 4 lanes store 4 points per tile (RNE)
            long p0 = (long)r * 1024 + c0 + it * 32;
            ushort4 oa, ob;
            oa.x = f2bf(pa[0] + b3s); oa.y = f2bf(pa[1] + b3s);
            oa.z = f2bf(pa[2] + b3s); oa.w = f2bf(pa[3] + b3s);
            ob.x = f2bf(pb[0] + b3s); ob.y = f2bf(pb[1] + b3s);
            ob.z = f2bf(pb[2] + b3s); ob.w = f2bf(pb[3] + b3s);
            *(ushort4*)(Wout + p0 + kq * 4)      = oa;
            *(ushort4*)(Wout + p0 + 16 + kq * 4) = ob;
        }
    }
}

// ---------------- stage B: out = x @ W^T + bias (bf16 MFMA) ----------------
// A = x_bf16 [8192][1024] K-contig; B = W_bf16 [1024][1024] (n=r, k=c) K-contig.
// Block: 256 thr = 4 waves (2x2 of 64x64), tile 128x128, BK=32.
// LDS chunk swizzle: row r (64B = 4 x 16B chunks), stored chunk p holds logical
// chunk p ^ ((r>>1)&3); staging lane fetches the matching global chunk.
__global__ __launch_bounds__(256) void gemm_kernel(
        const unsigned short* __restrict__ A,
        const unsigned short* __restrict__ B,
        const float* __restrict__ bias,
        float* __restrict__ C) {
    const int K = 1024;
    __shared__ __align__(16) unsigned short As[128 * 32];
    __shared__ __align__(16) unsigned short Bs[128 * 32];

    int tid  = threadIdx.x;
    int lane = tid & 63;
    int wv   = tid >> 6;
    int wm   = wv & 1, wn = wv >> 1;
    long Abase = (long)blockIdx.x * 128 * K;
    long Bbase = (long)blockIdx.y * 128 * K;

    int sr = tid >> 2;      // staging row 0..63 (+64 on round q=1)
    int sc = tid & 3;       // staging chunk slot
    int rsel = lane & 15;   // fragment row/col within 16
    int csel = lane >> 4;   // fragment k-chunk 0..3

    f32x4 acc[4][4] = {};

    for (int kt = 0; kt < K; kt += 32) {
        #pragma unroll
        for (int q = 0; q < 2; ++q) {
            int row = q * 64 + sr;
            int cc  = sc ^ ((row >> 1) & 3);                 // global chunk to fetch
            const unsigned short* ga = A + Abase + (long)row * K + kt + cc * 8;
            const unsigned short* gb = B + Bbase + (long)row * K + kt + cc * 8;
            unsigned short* la = &As[(q * 256 + wv * 64) * 8];  // wave-uniform base
            unsigned short* lb = &Bs[(q * 256 + wv * 64) * 8];
            async_ld16(ga, la);
            async_ld16(gb, lb);
        }
        __syncthreads();

        bf16x8 af[4], bf[4];
        #pragma unroll
        for (int mi = 0; mi < 4; ++mi) {
            int row = wm * 64 + mi * 16 + rsel;
            int ch  = csel ^ ((row >> 1) & 3);
            af[mi] = *(const bf16x8*)&As[row * 32 + ch * 8];
        }
        #pragma unroll
        for (int ni = 0; ni < 4; ++ni) {
            int row = wn * 64 + ni * 16 + rsel;
            int ch  = csel ^ ((row >> 1) & 3);
            bf[ni] = *(const bf16x8*)&Bs[row * 32 + ch * 8];
        }
        #pragma unroll
        for (int mi = 0; mi < 4; ++mi)
            #pragma unroll
            for (int ni = 0; ni < 4; ++ni)
                acc[mi][ni] = __builtin_amdgcn_mfma_f32_16x16x32_bf16(
                    af[mi], bf[ni], acc[mi][ni], 0, 0, 0);
        __syncthreads();
    }

    // epilogue: C/D layout col=lane&15, row=(lane>>4)*4+reg  (m89/m91 verified)
    int row0 = blockIdx.x * 128 + wm * 64;
    int col0 = blockIdx.y * 128 + wn * 64;
    #pragma unroll
    for (int ni = 0; ni < 4; ++ni) {
        int col = col0 + ni * 16 + rsel;
        float bv = bias[col];
        #pragma unroll
        for (int mi = 0; mi < 4; ++mi) {
            int rbase = row0 + mi * 16 + csel * 4;
            #pragma unroll
            for (int r = 0; r < 4; ++r)
                C[(long)(rbase + r) * 1024 + col] = acc[mi][ni][r] + bv;
        }
    }
}

extern "C" void kernel_launch(void* const* d_in, const int* in_sizes, int n_in,
                              void* d_out, int out_size, void* d_ws, size_t ws_size,
                              hipStream_t stream) {
    const float* x    = (const float*)d_in[0];
    const float* ec   = (const float*)d_in[1];
    const float* W1   = (const float*)d_in[2];
    const float* b1   = (const float*)d_in[3];
    const float* W2   = (const float*)d_in[4];
    const float* b2   = (const float*)d_in[5];
    const float* W3   = (const float*)d_in[6];
    const float* b3   = (const float*)d_in[7];
    const float* bias = (const float*)d_in[8];
    float* out = (float*)d_out;

    unsigned short* xb = (unsigned short*)d_ws;            // 8192*1024 bf16 = 16 MB
    unsigned short* Wb = xb + (size_t)8192 * 1024;         // 1024*1024 bf16 = 2 MB
    float* Zrow = (float*)(Wb + (size_t)1024 * 1024);      // 1024*64 f32 = 256 KB
    float* Zcol = Zrow + 1024 * 64;                        // 1024*64 f32 = 256 KB

    cast_x_kernel<<<8192, 256, 0, stream>>>((const float4*)x, xb);
    siren_tables_kernel<<<512, 256, 0, stream>>>(ec, W1, b1, Zrow, Zcol);
    siren_w_kernel<<<1024, 256, 0, stream>>>(Zrow, Zcol, W2, b2, W3, b3, Wb);
    dim3 g(64, 8);
    gemm_kernel<<<g, 256, 0, stream>>>(xb, Wb, bias, out);
}

// Round 7
// 206.754 us; speedup vs baseline: 1.8340x; 1.0137x over previous
//
#include <hip/hip_runtime.h>
#include <hip/hip_bf16.h>

// SirenLinear: out[b,r] = sum_c x[b,c] * W[r,c] + bias[r]
//   W[r,c] = b3 + h2 . W3,  h2 = sin(30*(W2 h1 + b2)),  h1 = sin(30*(W1 e + b1))
//
// Layer 1 exactly separable: z1(r,c) = Zrow[r] + Zcol[c]; tables/W2/b2 are
// pre-scaled by 30/(2pi) so each sine is one raw v_sin_f32. Layer 2 is MFMA.
// Round-6 lessons: all kernels now < 45 us; ~110 us of the wall is harness
// reset traffic (288 MiB d_ws poison + d_in restore) we can't touch. This
// round: gemm BK=64 (half the barrier drains, 32 MFMA/barrier), merged
// cast+tables prep kernel (one less launch).

typedef __attribute__((ext_vector_type(8))) short bf16x8;
typedef __attribute__((ext_vector_type(4))) float f32x4;

#define SIN_SCALE 4.77464829275686f   // 30 / (2*pi)

__device__ __forceinline__ unsigned short f2bf(float f) {
    union { float f; unsigned u; } v; v.f = f;
    unsigned r = v.u + 0x7fffu + ((v.u >> 16) & 1u);   // RNE
    return (unsigned short)(r >> 16);
}

// pack 2 floats -> 2 bf16 by truncation (cheap; RNE kept for final store)
__device__ __forceinline__ unsigned pktrunc(float a, float b) {
    union { float f; unsigned u; } x, y; x.f = a; y.f = b;
    return (x.u >> 16) | (y.u & 0xffff0000u);
}

// sin(2*pi*x) -- raw v_sin_f32, valid |x| <= 256 revs (here |x| <= ~8.3)
__device__ __forceinline__ float sinrev(float x) {
    return __builtin_amdgcn_sinf(x);
}

// butterfly add over lane^m (bitmode ds_swizzle)
template <int OFF>
__device__ __forceinline__ float swz_add(float v) {
    return v + __int_as_float(__builtin_amdgcn_ds_swizzle(__float_as_int(v), OFF));
}

__device__ __forceinline__ void async_ld16(const void* g, void* l) {
    __builtin_amdgcn_global_load_lds(
        (__attribute__((address_space(1))) void*)g,
        (__attribute__((address_space(3))) void*)l, 16, 0, 0);
}

// ---------------- prep: cast x -> bf16  +  layer-1 tables ----------------
// blocks [0,8192): cast 8M floats (one float4/thread).
// blocks [8192,8704): Zrow[r][j] = S*(W1[j,:].e(r,0)+b1[j]);
//                     Zcol[c][j] = S*(W1[j,:].(e(0,c)-e(0,0)))
__global__ __launch_bounds__(256) void prep_kernel(
        const float4* __restrict__ x, unsigned short* __restrict__ xb,
        const float* __restrict__ ec,
        const float* __restrict__ W1, const float* __restrict__ b1,
        float* __restrict__ Zrow, float* __restrict__ Zcol) {
    int b = blockIdx.x;
    if (b < 8192) {
        long i = (long)b * 256 + threadIdx.x;
        float4 v = x[i];
        ushort4 o;
        o.x = f2bf(v.x); o.y = f2bf(v.y); o.z = f2bf(v.z); o.w = f2bf(v.w);
        *(ushort4*)(xb + i * 4) = o;
    } else {
        int idx = (b - 8192) * 256 + threadIdx.x;    // 0..131071
        int j = idx & 63;
        int t = idx >> 6;                            // 0..2047
        const float* wr = W1 + j * 18;
        if (t < 1024) {
            const float* pe = ec + (long)t * 1024 * 18;   // point (r=t, c=0)
            float z = b1[j];
            #pragma unroll
            for (int i = 0; i < 18; ++i) z += wr[i] * pe[i];
            Zrow[t * 64 + j] = SIN_SCALE * z;
        } else {
            int c = t - 1024;
            const float* pe = ec + (long)c * 18;          // point (r=0, c)
            float z = 0.f;
            #pragma unroll
            for (int i = 0; i < 18; ++i) z += wr[i] * (pe[i] - ec[i]);
            Zcol[c * 64 + j] = SIN_SCALE * z;
        }
    }
}

// ---------------- stage A: generate W (bf16) via MFMA ----------------
// Wave covers 256 consecutive points of one row: 8 iters x 2 interleaved
// 16-pt tiles. A-frag: m=ln (point), k=kq*8+j (+32 for *1). B-frag: n=nt*16+ln.
// C/D: col=ln (=n), row=kq*4+rg (=point) [m89/m91 layouts].
__global__ __launch_bounds__(256, 3) void siren_w_kernel(
        const float* __restrict__ Zrow, const float* __restrict__ Zcol,
        const float* __restrict__ W2, const float* __restrict__ b2,
        const float* __restrict__ W3, const float* __restrict__ b3,
        unsigned short* __restrict__ Wout) {
    int lane = threadIdx.x & 63;
    int wv   = threadIdx.x >> 6;
    int ln   = lane & 15;
    int kq   = lane >> 4;

    // Preload B-frags of S*W2 (trunc bf16), S*b2, W3
    bf16x8 bfrag[2][4];
    #pragma unroll
    for (int kc = 0; kc < 2; ++kc)
        #pragma unroll
        for (int nt = 0; nt < 4; ++nt) {
            const float* src = W2 + (nt * 16 + ln) * 64 + kc * 32 + kq * 8;
            union { bf16x8 v; unsigned u[4]; } tmp;
            #pragma unroll
            for (int q = 0; q < 4; ++q)
                tmp.u[q] = pktrunc(SIN_SCALE * src[2*q], SIN_SCALE * src[2*q + 1]);
            bfrag[kc][nt] = tmp.v;
        }
    float b2v[4], w3v[4];
    #pragma unroll
    for (int nt = 0; nt < 4; ++nt) {
        b2v[nt] = SIN_SCALE * b2[nt * 16 + ln];
        w3v[nt] = W3[nt * 16 + ln];
    }
    float b3s = b3[0];

    int wid = blockIdx.x * 4 + wv;          // 0..4095 waves
    int r   = wid >> 2;                     // 4 waves per row
    int c0  = (wid & 3) * 256;

    // wave-invariant Zrow fragment (k = kq*8+j and 32+kq*8+j)
    const float* zrp = Zrow + (long)r * 64 + kq * 8;
    float zr0[8], zr1[8];
    #pragma unroll
    for (int j = 0; j < 8; ++j) { zr0[j] = zrp[j]; zr1[j] = zrp[32 + j]; }

    for (int it = 0; it < 8; ++it) {
        int ca = c0 + it * 32 + ln;                 // tile A point col
        const float* zca = Zcol + (long)ca * 64 + kq * 8;
        const float* zcb = zca + 16 * 64;           // tile B: +16 cols

        float sa0[8], sa1[8], sb0[8], sb1[8];
        #pragma unroll
        for (int j = 0; j < 8; ++j) {
            sa0[j] = sinrev(zr0[j] + zca[j]);
            sa1[j] = sinrev(zr1[j] + zca[32 + j]);
            sb0[j] = sinrev(zr0[j] + zcb[j]);
            sb1[j] = sinrev(zr1[j] + zcb[32 + j]);
        }
        union { bf16x8 v; unsigned u[4]; } a0, a1, bb0, bb1;
        #pragma unroll
        for (int q = 0; q < 4; ++q) {
            a0.u[q]  = pktrunc(sa0[2*q], sa0[2*q + 1]);
            a1.u[q]  = pktrunc(sa1[2*q], sa1[2*q + 1]);
            bb0.u[q] = pktrunc(sb0[2*q], sb0[2*q + 1]);
            bb1.u[q] = pktrunc(sb1[2*q], sb1[2*q + 1]);
        }

        f32x4 acca[4] = {}, accb[4] = {};
        #pragma unroll
        for (int nt = 0; nt < 4; ++nt) {
            acca[nt] = __builtin_amdgcn_mfma_f32_16x16x32_bf16(a0.v,  bfrag[0][nt], acca[nt], 0, 0, 0);
            accb[nt] = __builtin_amdgcn_mfma_f32_16x16x32_bf16(bb0.v, bfrag[0][nt], accb[nt], 0, 0, 0);
            acca[nt] = __builtin_amdgcn_mfma_f32_16x16x32_bf16(a1.v,  bfrag[1][nt], acca[nt], 0, 0, 0);
            accb[nt] = __builtin_amdgcn_mfma_f32_16x16x32_bf16(bb1.v, bfrag[1][nt], accb[nt], 0, 0, 0);
        }

        float pa[4], pb[4];
        #pragma unroll
        for (int rg = 0; rg < 4; ++rg) {
            float s = 0.f, t2 = 0.f;
            #pragma unroll
            for (int nt = 0; nt < 4; ++nt) {
                s  += w3v[nt] * sinrev(acca[nt][rg] + b2v[nt]);
                t2 += w3v[nt] * sinrev(accb[nt][rg] + b2v[nt]);
            }
            pa[rg] = s; pb[rg] = t2;
        }
        #pragma unroll
        for (int rg = 0; rg < 4; ++rg) {
            pa[rg] = swz_add<0x041F>(pa[rg]);  pb[rg] = swz_add<0x041F>(pb[rg]);
            pa[rg] = swz_add<0x081F>(pa[rg]);  pb[rg] = swz_add<0x081F>(pb[rg]);
            pa[rg] = swz_add<0x101F>(pa[rg]);  pb[rg] = swz_add<0x101F>(pb[rg]);
            pa[rg] = swz_add<0x201F>(pa[rg]);  pb[rg] = swz_add<0x201F>(pb[rg]);
        }

        if (ln == 0) {                       // 4 lanes store 4 points per tile (RNE)
            long p0 = (long)r * 1024 + c0 + it * 32;
            ushort4 oa, ob;
            oa.x = f2bf(pa[0] + b3s); oa.y = f2bf(pa[1] + b3s);
            oa.z = f2bf(pa[2] + b3s); oa.w = f2bf(pa[3] + b3s);
            ob.x = f2bf(pb[0] + b3s); ob.y = f2bf(pb[1] + b3s);
            ob.z = f2bf(pb[2] + b3s); ob.w = f2bf(pb[3] + b3s);
            *(ushort4*)(Wout + p0 + kq * 4)      = oa;
            *(ushort4*)(Wout + p0 + 16 + kq * 4) = ob;
        }
    }
}

// ---------------- stage B: out = x @ W^T + bias (bf16 MFMA) ----------------
// A = x_bf16 [8192][1024] K-contig; B = W_bf16 [1024][1024] (n=r, k=c) K-contig.
// Block: 256 thr = 4 waves (2x2 of 64x64), tile 128x128, BK=64 (16 barriers,
// 32 MFMA/wave per barrier -- halves the vmcnt(0) drain count vs BK=32).
// Row = 128 B = 8 chunks of 16 B; stored position p holds logical chunk
// p ^ (row&7) (staging fetches the matching global chunk; m104-legal since
// LDS dest stays linear in lane). Fragment reads hit all 8 positions ->
// 2 lanes/bank = free (m136).
__global__ __launch_bounds__(256) void gemm_kernel(
        const unsigned short* __restrict__ A,
        const unsigned short* __restrict__ B,
        const float* __restrict__ bias,
        float* __restrict__ C) {
    const int K = 1024;
    __shared__ __align__(16) unsigned short As[128 * 64];
    __shared__ __align__(16) unsigned short Bs[128 * 64];

    int tid  = threadIdx.x;
    int lane = tid & 63;
    int wv   = tid >> 6;
    int wm   = wv & 1, wn = wv >> 1;
    long Abase = (long)blockIdx.x * 128 * K;
    long Bbase = (long)blockIdx.y * 128 * K;

    int sr8 = tid >> 3;     // staging row 0..31 (+32q)
    int sl  = tid & 7;      // staging chunk slot
    int rsel = lane & 15;   // fragment m/n within 16
    int kq   = lane >> 4;   // fragment k-quad 0..3

    f32x4 acc[4][4] = {};

    for (int kt = 0; kt < K; kt += 64) {
        #pragma unroll
        for (int q = 0; q < 4; ++q) {
            int row = q * 32 + sr8;
            int cc  = sl ^ (row & 7);                        // global chunk to fetch
            const unsigned short* ga = A + Abase + (long)row * K + kt + cc * 8;
            const unsigned short* gb = B + Bbase + (long)row * K + kt + cc * 8;
            unsigned short* la = &As[(q * 256 + wv * 64) * 8];  // wave-uniform base
            unsigned short* lb = &Bs[(q * 256 + wv * 64) * 8];
            async_ld16(ga, la);
            async_ld16(gb, lb);
        }
        __syncthreads();

        #pragma unroll
        for (int h = 0; h < 2; ++h) {
            bf16x8 af[4], bf[4];
            #pragma unroll
            for (int mi = 0; mi < 4; ++mi) {
                int row = wm * 64 + mi * 16 + rsel;
                int ch  = (h * 4 + kq) ^ (row & 7);
                af[mi] = *(const bf16x8*)&As[row * 64 + ch * 8];
            }
            #pragma unroll
            for (int ni = 0; ni < 4; ++ni) {
                int row = wn * 64 + ni * 16 + rsel;
                int ch  = (h * 4 + kq) ^ (row & 7);
                bf[ni] = *(const bf16x8*)&Bs[row * 64 + ch * 8];
            }
            #pragma unroll
            for (int mi = 0; mi < 4; ++mi)
                #pragma unroll
                for (int ni = 0; ni < 4; ++ni)
                    acc[mi][ni] = __builtin_amdgcn_mfma_f32_16x16x32_bf16(
                        af[mi], bf[ni], acc[mi][ni], 0, 0, 0);
        }
        __syncthreads();
    }

    // epilogue: C/D layout col=lane&15, row=(lane>>4)*4+reg  (m89/m91 verified)
    int row0 = blockIdx.x * 128 + wm * 64;
    int col0 = blockIdx.y * 128 + wn * 64;
    #pragma unroll
    for (int ni = 0; ni < 4; ++ni) {
        int col = col0 + ni * 16 + rsel;
        float bv = bias[col];
        #pragma unroll
        for (int mi = 0; mi < 4; ++mi) {
            int rbase = row0 + mi * 16 + kq * 4;
            #pragma unroll
            for (int r = 0; r < 4; ++r)
                C[(long)(rbase + r) * 1024 + col] = acc[mi][ni][r] + bv;
        }
    }
}

extern "C" void kernel_launch(void* const* d_in, const int* in_sizes, int n_in,
                              void* d_out, int out_size, void* d_ws, size_t ws_size,
                              hipStream_t stream) {
    const float* x    = (const float*)d_in[0];
    const float* ec   = (const float*)d_in[1];
    const float* W1   = (const float*)d_in[2];
    const float* b1   = (const float*)d_in[3];
    const float* W2   = (const float*)d_in[4];
    const float* b2   = (const float*)d_in[5];
    const float* W3   = (const float*)d_in[6];
    const float* b3   = (const float*)d_in[7];
    const float* bias = (const float*)d_in[8];
    float* out = (float*)d_out;

    unsigned short* xb = (unsigned short*)d_ws;            // 8192*1024 bf16 = 16 MB
    unsigned short* Wb = xb + (size_t)8192 * 1024;         // 1024*1024 bf16 = 2 MB
    float* Zrow = (float*)(Wb + (size_t)1024 * 1024);      // 1024*64 f32 = 256 KB
    float* Zcol = Zrow + 1024 * 64;                        // 1024*64 f32 = 256 KB

    prep_kernel<<<8704, 256, 0, stream>>>((const float4*)x, xb, ec, W1, b1, Zrow, Zcol);
    siren_w_kernel<<<1024, 256, 0, stream>>>(Zrow, Zcol, W2, b2, W3, b3, Wb);
    dim3 g(64, 8);
    gemm_kernel<<<g, 256, 0, stream>>>(xb, Wb, bias, out);
}